// Round 1
// baseline (1402.134 us; speedup 1.0000x reference)
//
#include <hip/hip_runtime.h>

#define NEDGES 65536
#define NNODES 8192
#define EPB 64              // edges per block
#define NBLK (NEDGES/EPB)   // 1024

// constants
#define PW0f       0.14433756729740643f   // (1/48)^0.5
#define PW1f       0.21650635094610965f   // (3/64)^0.5
#define INV_SQRT3f 0.5773502691896258f
#define INV_SQRT6f 0.4082482904638631f
#define SILU_NORMf 1.6790425f

__device__ __forceinline__ float silu_n(float z) {
    return SILU_NORMf * z / (1.0f + __expf(-z));
}

// ---------------------------------------------------------------------------
// Kernel 1: self-connection, overwrites d_out (re-initializes it every call)
// out[n, s<32]   = sum_u n0[u] * Wsc0[u,s] / sqrt(32)
// out[n, 32+v*3+k] = sum_u n1[u,k] * Wsc1[u,v] / 4
// ---------------------------------------------------------------------------
__global__ void k_selfconn(const float* __restrict__ node_feat,
                           const float* __restrict__ Wsc0,
                           const float* __restrict__ Wsc1,
                           float* __restrict__ out)
{
    int gid = blockIdx.x * 256 + threadIdx.x;
    if (gid >= NNODES * 80) return;
    int n = gid / 80;
    int s = gid - n * 80;
    const float* nf = node_feat + (size_t)n * 80;
    float r;
    if (s < 32) {
        float a = 0.f;
        #pragma unroll
        for (int u = 0; u < 32; ++u) a += nf[u] * Wsc0[u * 32 + s];
        r = a * 0.17677669529663687f;   // 1/sqrt(32)
    } else {
        int v = (s - 32) / 3;
        int k = (s - 32) - v * 3;
        float a = 0.f;
        #pragma unroll
        for (int u = 0; u < 16; ++u) a += nf[32 + u * 3 + k] * Wsc1[u * 16 + v];
        r = a * 0.25f;                   // 1/sqrt(16)
    }
    out[gid] = r;
}

// ---------------------------------------------------------------------------
// Kernel 2: fused radial-MLP + tensor product + scatter-add.
// Block = 256 threads = 4 waves, handles 64 edges.
//   Phase A : compute h1 = silu-MLP(edge_embed) for the 64 edges -> LDS
//   Phase A2: per-edge left factors (x0, x1, cross, dot, y0, y1) -> LDS
//   Main    : lane = edge; each wave covers 640 of the 2560 fc2 columns in
//             32-col register chunks (wave-uniform s_load of W_fc2 rows),
//             contracting immediately into per-edge msg[80] registers.
//   Reduce  : LDS atomic combine across waves, then global atomicAdd to out.
// ---------------------------------------------------------------------------
__global__ __launch_bounds__(256, 2) void k_main(
    const int*   __restrict__ eidx,
    const float* __restrict__ node_feat,
    const float* __restrict__ edge_feat,
    const float* __restrict__ edge_embed,
    const float* __restrict__ Wfc0,
    const float* __restrict__ Wfc1,
    const float* __restrict__ Wfc2,
    float*       __restrict__ out)
{
    __shared__ float h1S[64 * 65];     // [edge][dim], pad 65 for bank-free lane-strided read
    __shared__ float leftS[64 * 149];  // [edge][x0:0..31, x1:32..79, cross:80..127, dot:128..143, y0:144, y1:145..147]
    __shared__ float msgS[64 * 81];    // [edge][80], pad 81
    __shared__ int   dstS[64];

    const int t    = threadIdx.x;
    const int lane = t & 63;
    const int wid  = t >> 6;
    const int eg0  = blockIdx.x * EPB;

    // Phase A: radial MLP layers 1-2. embS/h0S alias the (not-yet-live) leftS.
    float* embS = leftS;            // 64*64
    float* h0S  = leftS + 4096;     // 64*64
    {
        const int ebase = wid * 16;  // this wave's 16 edges
        for (int r = 0; r < 16; ++r)
            embS[(ebase + r) * 64 + lane] =
                edge_embed[(size_t)(eg0 + ebase + r) * 64 + lane];
        __syncthreads();

        float acc[16];
        #pragma unroll
        for (int r = 0; r < 16; ++r) acc[r] = 0.f;
        for (int c = 0; c < 64; ++c) {
            float w0 = Wfc0[c * 64 + lane];
            #pragma unroll
            for (int r = 0; r < 16; ++r) acc[r] += embS[(ebase + r) * 64 + c] * w0;
        }
        __syncthreads();
        #pragma unroll
        for (int r = 0; r < 16; ++r) h0S[(ebase + r) * 64 + lane] = silu_n(0.125f * acc[r]);
        __syncthreads();

        #pragma unroll
        for (int r = 0; r < 16; ++r) acc[r] = 0.f;
        for (int c = 0; c < 64; ++c) {
            float w1 = Wfc1[c * 64 + lane];
            #pragma unroll
            for (int r = 0; r < 16; ++r) acc[r] += h0S[(ebase + r) * 64 + c] * w1;
        }
        #pragma unroll
        for (int r = 0; r < 16; ++r) h1S[(ebase + r) * 65 + lane] = silu_n(0.125f * acc[r]);
        __syncthreads();   // h0S dead; leftS region free for phase A2
    }

    // Phase A2: left factors, 4 threads per edge (q = part)
    {
        const int q  = wid;
        const int eg = eg0 + lane;
        const int src = eidx[eg];
        if (q == 0) dstS[lane] = eidx[NEDGES + eg];
        float* Lp = leftS + lane * 149;
        const float* nf = node_feat + (size_t)src * 80;
        const float* ef = edge_feat + (size_t)eg * 4;
        if (q == 0) {
            #pragma unroll
            for (int u = 0; u < 32; ++u) Lp[u] = nf[u];
            Lp[144] = ef[0]; Lp[145] = ef[1]; Lp[146] = ef[2]; Lp[147] = ef[3];
        } else if (q == 1) {
            #pragma unroll
            for (int j = 0; j < 48; ++j) Lp[32 + j] = nf[32 + j];
        } else if (q == 2) {
            float ya = ef[1], yb = ef[2], yc = ef[3];
            #pragma unroll
            for (int u = 0; u < 16; ++u)
                Lp[128 + u] = nf[32 + u * 3] * ya + nf[32 + u * 3 + 1] * yb + nf[32 + u * 3 + 2] * yc;
        } else {
            float ya = ef[1], yb = ef[2], yc = ef[3];
            #pragma unroll
            for (int u = 0; u < 16; ++u) {
                float xa = nf[32 + u * 3], xb = nf[32 + u * 3 + 1], xc = nf[32 + u * 3 + 2];
                Lp[80 + u * 3 + 0] = xb * yc - xc * yb;
                Lp[80 + u * 3 + 1] = xc * ya - xa * yc;
                Lp[80 + u * 3 + 2] = xa * yb - xb * ya;
            }
        }
    }
    for (int idx = t; idx < 64 * 81; idx += 256) msgS[idx] = 0.f;
    __syncthreads();

    // Main phase: lane = edge, wave wid covers j in [wid*640, wid*640+640)
    {
        const float* Lp = leftS + lane * 149;
        const float y0 = Lp[144];
        const float y1x = Lp[145], y1y = Lp[146], y1z = Lp[147];
        float msg0[32], msg1[48];
        #pragma unroll
        for (int i = 0; i < 32; ++i) msg0[i] = 0.f;
        #pragma unroll
        for (int i = 0; i < 48; ++i) msg1[i] = 0.f;

        const int jlo = wid * 640, jhi = jlo + 640;
        for (int j0 = jlo; j0 < jhi; j0 += 32) {
            float acc[32];
            #pragma unroll
            for (int q = 0; q < 32; ++q) acc[q] = 0.f;
            #pragma unroll 4
            for (int c = 0; c < 64; ++c) {
                const float h = h1S[lane * 65 + c];
                const float4* wr = (const float4*)(Wfc2 + (size_t)c * 2560 + j0);
                float w4[32];
                #pragma unroll
                for (int q4 = 0; q4 < 8; ++q4) {
                    float4 v = wr[q4];   // wave-uniform address -> scalar load
                    w4[q4 * 4 + 0] = v.x; w4[q4 * 4 + 1] = v.y;
                    w4[q4 * 4 + 2] = v.z; w4[q4 * 4 + 3] = v.w;
                }
                #pragma unroll
                for (int q = 0; q < 32; ++q) acc[q] += h * w4[q];
            }
            // epilogue (regions aligned to 32; branch wave-uniform). 0.125 = W_fc2 / 8 fold.
            if (j0 < 1024) {                       // W1: j = u*32+w
                const int u = j0 >> 5;
                const float f = 0.125f * PW0f * y0 * Lp[u];
                #pragma unroll
                for (int q = 0; q < 32; ++q) msg0[q] += f * acc[q];
            } else if (j0 < 1536) {                // W2: j = 1024 + u*32 + w
                const int u = (j0 - 1024) >> 5;
                const float f = 0.125f * PW0f * INV_SQRT3f * Lp[128 + u];
                #pragma unroll
                for (int q = 0; q < 32; ++q) msg0[q] += f * acc[q];
            } else if (j0 < 2048) {                // W3: j = 1536 + u*16 + w
                const int u0 = (j0 - 1536) >> 4;
                #pragma unroll
                for (int h2 = 0; h2 < 2; ++h2) {
                    const float f = 0.125f * PW1f * INV_SQRT3f * Lp[u0 + h2];
                    #pragma unroll
                    for (int w = 0; w < 16; ++w) {
                        const float tv = f * acc[h2 * 16 + w];
                        msg1[w * 3 + 0] += tv * y1x;
                        msg1[w * 3 + 1] += tv * y1y;
                        msg1[w * 3 + 2] += tv * y1z;
                    }
                }
            } else if (j0 < 2304) {                // W4: j = 2048 + u*16 + w
                const int u0 = (j0 - 2048) >> 4;
                #pragma unroll
                for (int h2 = 0; h2 < 2; ++h2) {
                    const int u = u0 + h2;
                    const float fb = 0.125f * PW1f * INV_SQRT3f * y0;
                    const float fx = fb * Lp[32 + u * 3 + 0];
                    const float fy = fb * Lp[32 + u * 3 + 1];
                    const float fz = fb * Lp[32 + u * 3 + 2];
                    #pragma unroll
                    for (int w = 0; w < 16; ++w) {
                        const float av = acc[h2 * 16 + w];
                        msg1[w * 3 + 0] += fx * av;
                        msg1[w * 3 + 1] += fy * av;
                        msg1[w * 3 + 2] += fz * av;
                    }
                }
            } else {                               // W5: j = 2304 + u*16 + w
                const int u0 = (j0 - 2304) >> 4;
                #pragma unroll
                for (int h2 = 0; h2 < 2; ++h2) {
                    const int u = u0 + h2;
                    const float fb = 0.125f * PW1f * INV_SQRT6f;
                    const float fx = fb * Lp[80 + u * 3 + 0];
                    const float fy = fb * Lp[80 + u * 3 + 1];
                    const float fz = fb * Lp[80 + u * 3 + 2];
                    #pragma unroll
                    for (int w = 0; w < 16; ++w) {
                        const float av = acc[h2 * 16 + w];
                        msg1[w * 3 + 0] += fx * av;
                        msg1[w * 3 + 1] += fy * av;
                        msg1[w * 3 + 2] += fz * av;
                    }
                }
            }
        }

        // combine partial msg across waves in LDS
        float* M = msgS + lane * 81;
        if (jlo < 1536) {              // this wave touched out0
            #pragma unroll
            for (int q = 0; q < 32; ++q) atomicAdd(&M[q], msg0[q]);
        }
        if (jhi > 1536) {              // this wave touched out1
            #pragma unroll
            for (int s = 0; s < 48; ++s) atomicAdd(&M[32 + s], msg1[s]);
        }
    }
    __syncthreads();

    // scatter: 4 threads per edge, 20 slots each
    {
        const int e    = t & 63;
        const int part = t >> 6;
        const int d    = dstS[e];
        float* op = out + (size_t)d * 80;
        const float* M = msgS + e * 81;
        #pragma unroll
        for (int s = part * 20; s < part * 20 + 20; ++s)
            atomicAdd(&op[s], M[s]);
    }
}

extern "C" void kernel_launch(void* const* d_in, const int* in_sizes, int n_in,
                              void* d_out, int out_size, void* d_ws, size_t ws_size,
                              hipStream_t stream) {
    const int*   eidx       = (const int*)d_in[0];
    const float* node_feat  = (const float*)d_in[1];
    const float* edge_feat  = (const float*)d_in[2];
    const float* edge_embed = (const float*)d_in[3];
    const float* Wfc0       = (const float*)d_in[5];
    const float* Wfc1       = (const float*)d_in[6];
    const float* Wfc2       = (const float*)d_in[7];
    const float* Wsc0       = (const float*)d_in[8];
    const float* Wsc1       = (const float*)d_in[9];
    float* out = (float*)d_out;

    hipLaunchKernelGGL(k_selfconn, dim3((NNODES * 80 + 255) / 256), dim3(256), 0, stream,
                       node_feat, Wsc0, Wsc1, out);
    hipLaunchKernelGGL(k_main, dim3(NBLK), dim3(256), 0, stream,
                       eidx, node_feat, edge_feat, edge_embed,
                       Wfc0, Wfc1, Wfc2, out);
}

// Round 2
// 140.313 us; speedup vs baseline: 9.9929x; 9.9929x over previous
//
#include <hip/hip_runtime.h>

typedef unsigned short u16;
typedef __bf16 bf16x8 __attribute__((ext_vector_type(8)));
typedef float  f32x4  __attribute__((ext_vector_type(4)));

#define NEDGES 65536
#define NNODES 8192

#define PW0f       0.14433756729740643f   // (1/48)^0.5
#define PW1f       0.21650635094610965f   // (3/64)^0.5
#define INV_SQRT3f 0.5773502691896258f
#define INV_SQRT6f 0.4082482904638631f
#define SILU_NORMf 1.6790425f

// workspace layout (bf16 elements)
#define WT2_OFF 0          // [2560][64]  Wfc2^T, 0.125*region scale folded
#define WT0_OFF 163840     // [64][64]    Wfc0^T * 0.125
#define WT1_OFF 167936     // [64][64]    Wfc1^T * 0.125
#define WS_ELEMS 172032

#define HSTR 72            // padded bf16 row stride for h0/h1 LDS tiles

__device__ __forceinline__ float silu_n(float z) {
    return SILU_NORMf * z / (1.0f + __expf(-z));
}
__device__ __forceinline__ u16 f2bf(float f) {
    return __builtin_bit_cast(u16, (__bf16)f);
}
__device__ __forceinline__ float bf2f(u16 u) {
    unsigned v = ((unsigned)u) << 16;
    return __builtin_bit_cast(float, v);
}
__device__ __forceinline__ bf16x8 ld_bf8(const u16* p) {
    return *reinterpret_cast<const bf16x8*>(p);
}
__device__ __forceinline__ bf16x8 cvt_bf8(const float* p) {
    float4 a = *reinterpret_cast<const float4*>(p);
    float4 b = *reinterpret_cast<const float4*>(p + 4);
    bf16x8 r;
    r[0]=(__bf16)a.x; r[1]=(__bf16)a.y; r[2]=(__bf16)a.z; r[3]=(__bf16)a.w;
    r[4]=(__bf16)b.x; r[5]=(__bf16)b.y; r[6]=(__bf16)b.z; r[7]=(__bf16)b.w;
    return r;
}
#define MFMA16(A,B,C) __builtin_amdgcn_mfma_f32_16x16x32_bf16(A,B,C,0,0,0)

// ---------------------------------------------------------------------------
// Prepass: transpose + scale + bf16-convert the three MLP weights into d_ws.
// Region scales of the fc2 output folded in (columns j of w):
//   j<1024: PW0 | j<1536: PW0/sqrt3 | j<2304: PW1/sqrt3 | else: PW1/sqrt6
// ---------------------------------------------------------------------------
__global__ void k_pre(const float* __restrict__ Wfc0,
                      const float* __restrict__ Wfc1,
                      const float* __restrict__ Wfc2,
                      u16* __restrict__ ws)
{
    int gid = blockIdx.x * 256 + threadIdx.x;
    if (gid < 163840) {                 // gid = k*2560 + j  (read-coalesced)
        int k = gid / 2560;
        int j = gid - k * 2560;
        float s;
        if (j < 1024)      s = PW0f;
        else if (j < 1536) s = PW0f * INV_SQRT3f;
        else if (j < 2304) s = PW1f * INV_SQRT3f;
        else               s = PW1f * INV_SQRT6f;
        ws[WT2_OFF + j * 64 + k] = f2bf(Wfc2[gid] * (0.125f * s));
    } else if (gid < WT1_OFF) {
        int i = gid - WT0_OFF;          // i = k*64 + n
        int k = i >> 6, n = i & 63;
        ws[WT0_OFF + n * 64 + k] = f2bf(Wfc0[i] * 0.125f);
    } else if (gid < WS_ELEMS) {
        int i = gid - WT1_OFF;
        int k = i >> 6, n = i & 63;
        ws[WT1_OFF + n * 64 + k] = f2bf(Wfc1[i] * 0.125f);
    }
}

// ---------------------------------------------------------------------------
// Self-connection: initializes d_out (overwrites every call).
// ---------------------------------------------------------------------------
__global__ void k_selfconn(const float* __restrict__ node_feat,
                           const float* __restrict__ Wsc0,
                           const float* __restrict__ Wsc1,
                           float* __restrict__ out)
{
    int gid = blockIdx.x * 256 + threadIdx.x;
    if (gid >= NNODES * 80) return;
    int n = gid / 80;
    int s = gid - n * 80;
    const float* nf = node_feat + (size_t)n * 80;
    float r;
    if (s < 32) {
        float a = 0.f;
        #pragma unroll
        for (int u = 0; u < 32; ++u) a += nf[u] * Wsc0[u * 32 + s];
        r = a * 0.17677669529663687f;
    } else {
        int v = (s - 32) / 3;
        int k = (s - 32) - v * 3;
        float a = 0.f;
        #pragma unroll
        for (int u = 0; u < 16; ++u) a += nf[32 + u * 3 + k] * Wsc1[u * 16 + v];
        r = a * 0.25f;
    }
    out[gid] = r;
}

// ---------------------------------------------------------------------------
// Main fused kernel: 64 edges / block, 4 waves.
//  - fc0/fc1 via MFMA (A = transposed weights, B = 16 edges per wave)
//  - main fc2 loop: wave w owns columns [w*640, w*640+640) in 16-col tiles;
//    A = WT2 tile (global/L2), B = h1 fragments (regs, loaded once);
//    MFMA result contracted immediately against LDS left-factors into
//    80 msg registers per lane (all 64 edges per wave via 4 e-groups).
//  - LDS atomic cross-wave reduce, then global atomic scatter on dst.
// ---------------------------------------------------------------------------
__global__ __launch_bounds__(256, 2) void k_main(
    const int*   __restrict__ eidx,
    const float* __restrict__ node_feat,
    const float* __restrict__ edge_feat,
    const float* __restrict__ edge_embed,
    const u16*   __restrict__ ws,
    float*       __restrict__ out)
{
    __shared__ __align__(16) char smem[50432];
    u16*   h0S  = (u16*)(smem);             // [64][HSTR]  9216 B
    u16*   h1S  = (u16*)(smem + 9216);      // [64][HSTR]  9216 B
    float* x0S  = (float*)(smem + 18432);   // [32][64]    8192 B  (raw x0)
    float* LdS  = (float*)(smem + 26624);   // [16][64]    4096 B  (dot)
    float* x1S  = (float*)(smem + 30720);   // [48][64]   12288 B  (x1, k-major rows u*3+k)
    u16*   crS  = (u16*)(smem + 43008);     // [48][64]    6144 B  (cross, bf16)
    float* y0S  = (float*)(smem + 49152);   // [64]
    float* y1S  = (float*)(smem + 49408);   // [3][64]
    int*   dstS = (int*)(smem + 50176);     // [64]
    float* msgS = (float*)(smem);           // [64][81] 20736 B, aliases h0/h1/x0-head (dead by then)

    const int t    = threadIdx.x;
    const int lane = t & 63;
    const int l15  = lane & 15;
    const int lq   = lane >> 4;
    const int w    = t >> 6;
    const int eg0  = blockIdx.x * 64;

    const u16* WT2 = ws + WT2_OFF;
    const u16* WT0 = ws + WT0_OFF;
    const u16* WT1 = ws + WT1_OFF;

    // ---------------- fc0: h0 = silu(emb @ W0/8), 16 edges per wave --------
    {
        const float* erow = edge_embed + (size_t)(eg0 + w * 16 + l15) * 64 + 8 * lq;
        bf16x8 eB0 = cvt_bf8(erow);
        bf16x8 eB1 = cvt_bf8(erow + 32);
        #pragma unroll
        for (int nt = 0; nt < 4; ++nt) {
            const u16* a = WT0 + (nt * 16 + l15) * 64 + 8 * lq;
            bf16x8 A0 = ld_bf8(a);
            bf16x8 A1 = ld_bf8(a + 32);
            f32x4 z = {0.f, 0.f, 0.f, 0.f};
            z = MFMA16(A0, eB0, z);
            f32x4 dd = MFMA16(A1, eB1, z);
            ushort4 pk;
            pk.x = f2bf(silu_n(dd[0]));
            pk.y = f2bf(silu_n(dd[1]));
            pk.z = f2bf(silu_n(dd[2]));
            pk.w = f2bf(silu_n(dd[3]));
            *(ushort4*)&h0S[(w * 16 + l15) * HSTR + nt * 16 + lq * 4] = pk;
        }
    }
    // ---------------- fc1: h1 = silu(h0 @ W1/8) ----------------------------
    {
        const u16* hrow = h0S + (w * 16 + l15) * HSTR + 8 * lq;
        bf16x8 hB0 = ld_bf8(hrow);
        bf16x8 hB1 = ld_bf8(hrow + 32);
        #pragma unroll
        for (int nt = 0; nt < 4; ++nt) {
            const u16* a = WT1 + (nt * 16 + l15) * 64 + 8 * lq;
            bf16x8 A0 = ld_bf8(a);
            bf16x8 A1 = ld_bf8(a + 32);
            f32x4 z = {0.f, 0.f, 0.f, 0.f};
            z = MFMA16(A0, hB0, z);
            f32x4 dd = MFMA16(A1, hB1, z);
            ushort4 pk;
            pk.x = f2bf(silu_n(dd[0]));
            pk.y = f2bf(silu_n(dd[1]));
            pk.z = f2bf(silu_n(dd[2]));
            pk.w = f2bf(silu_n(dd[3]));
            *(ushort4*)&h1S[(w * 16 + l15) * HSTR + nt * 16 + lq * 4] = pk;
        }
    }

    // ---------------- left factors, 4 threads per edge ---------------------
    {
        const int e   = t & 63;
        const int qq  = t >> 6;
        const int eg  = eg0 + e;
        const int src = eidx[eg];
        const float* nf = node_feat + (size_t)src * 80;
        const float* ef = edge_feat + (size_t)eg * 4;
        if (qq == 0) {
            dstS[e] = eidx[NEDGES + eg];
            y0S[e] = ef[0];
            y1S[e] = ef[1]; y1S[64 + e] = ef[2]; y1S[128 + e] = ef[3];
            #pragma unroll
            for (int u = 0; u < 32; ++u) x0S[u * 64 + e] = nf[u];
        } else if (qq == 1) {
            #pragma unroll
            for (int j = 0; j < 48; ++j) x1S[j * 64 + e] = nf[32 + j];
        } else if (qq == 2) {
            float ya = ef[1], yb = ef[2], yc = ef[3];
            #pragma unroll
            for (int u = 0; u < 16; ++u)
                LdS[u * 64 + e] = nf[32 + u * 3] * ya + nf[32 + u * 3 + 1] * yb
                                + nf[32 + u * 3 + 2] * yc;
        } else {
            float ya = ef[1], yb = ef[2], yc = ef[3];
            #pragma unroll
            for (int u = 0; u < 16; ++u) {
                float xa = nf[32 + u * 3], xb = nf[32 + u * 3 + 1], xc = nf[32 + u * 3 + 2];
                crS[(u * 3 + 0) * 64 + e] = f2bf(xb * yc - xc * yb);
                crS[(u * 3 + 1) * 64 + e] = f2bf(xc * ya - xa * yc);
                crS[(u * 3 + 2) * 64 + e] = f2bf(xa * yb - xb * ya);
            }
        }
    }
    __syncthreads();

    // ---------------- B fragments (all 64 edges) + per-lane y regs ---------
    bf16x8 hb[4][2];
    float  y0r[4], y1r[4][3];
    #pragma unroll
    for (int eg = 0; eg < 4; ++eg) {
        const u16* r = h1S + (eg * 16 + l15) * HSTR + 8 * lq;
        hb[eg][0] = ld_bf8(r);
        hb[eg][1] = ld_bf8(r + 32);
        const int e = eg * 16 + l15;
        y0r[eg]    = y0S[e];
        y1r[eg][0] = y1S[e];
        y1r[eg][1] = y1S[64 + e];
        y1r[eg][2] = y1S[128 + e];
    }

    // ---------------- main fc2 loop -----------------------------------------
    float m0[4][2][4];   // [eg][half][r]  -> out0[e][half*16 + lq*4 + r]
    float m1[4][4][3];   // [eg][r][k]     -> out1[e][lq*4 + r][k]
    #pragma unroll
    for (int eg = 0; eg < 4; ++eg) {
        #pragma unroll
        for (int r = 0; r < 4; ++r) {
            m0[eg][0][r] = 0.f; m0[eg][1][r] = 0.f;
            m1[eg][r][0] = 0.f; m1[eg][r][1] = 0.f; m1[eg][r][2] = 0.f;
        }
    }

    const int jbase = w * 640;
    bf16x8 A0, A1;
    {
        const u16* p = WT2 + (size_t)(jbase + l15) * 64 + 8 * lq;
        A0 = ld_bf8(p); A1 = ld_bf8(p + 32);
    }
    for (int jt = 0; jt < 40; ++jt) {
        const int j0 = jbase + jt * 16;
        f32x4 d[4];
        #pragma unroll
        for (int eg = 0; eg < 4; ++eg) {
            f32x4 z = {0.f, 0.f, 0.f, 0.f};
            z = MFMA16(A0, hb[eg][0], z);
            d[eg] = MFMA16(A1, hb[eg][1], z);
        }
        bf16x8 nA0 = A0, nA1 = A1;
        if (jt < 39) {
            const u16* p = WT2 + (size_t)(j0 + 16 + l15) * 64 + 8 * lq;
            nA0 = ld_bf8(p); nA1 = ld_bf8(p + 32);
        }
        if (j0 < 1536) {                               // W1 / W2 -> msg0
            const float* base = (j0 < 1024) ? (x0S + (j0 >> 5) * 64)
                                            : (LdS + ((j0 - 1024) >> 5) * 64);
            const bool useY0 = (j0 < 1024);
            if ((j0 & 16) == 0) {
                #pragma unroll
                for (int eg = 0; eg < 4; ++eg) {
                    float f = base[eg * 16 + l15];
                    if (useY0) f *= y0r[eg];
                    #pragma unroll
                    for (int r = 0; r < 4; ++r) m0[eg][0][r] += f * d[eg][r];
                }
            } else {
                #pragma unroll
                for (int eg = 0; eg < 4; ++eg) {
                    float f = base[eg * 16 + l15];
                    if (useY0) f *= y0r[eg];
                    #pragma unroll
                    for (int r = 0; r < 4; ++r) m0[eg][1][r] += f * d[eg][r];
                }
            }
        } else if (j0 < 2048) {                        // W3: x0[u] * y1[k]
            const float* xs = x0S + ((j0 - 1536) >> 4) * 64;
            #pragma unroll
            for (int eg = 0; eg < 4; ++eg) {
                const float x = xs[eg * 16 + l15];
                #pragma unroll
                for (int r = 0; r < 4; ++r) {
                    const float tv = x * d[eg][r];
                    m1[eg][r][0] += tv * y1r[eg][0];
                    m1[eg][r][1] += tv * y1r[eg][1];
                    m1[eg][r][2] += tv * y1r[eg][2];
                }
            }
        } else if (j0 < 2304) {                        // W4: x1[u][k] * y0
            const float* xp = x1S + ((j0 - 2048) >> 4) * 192;
            #pragma unroll
            for (int eg = 0; eg < 4; ++eg) {
                const int e = eg * 16 + l15;
                const float g0 = xp[e]        * y0r[eg];
                const float g1 = xp[64 + e]   * y0r[eg];
                const float g2 = xp[128 + e]  * y0r[eg];
                #pragma unroll
                for (int r = 0; r < 4; ++r) {
                    m1[eg][r][0] += g0 * d[eg][r];
                    m1[eg][r][1] += g1 * d[eg][r];
                    m1[eg][r][2] += g2 * d[eg][r];
                }
            }
        } else {                                       // W5: cross[u][k]
            const u16* cp = crS + ((j0 - 2304) >> 4) * 192;
            #pragma unroll
            for (int eg = 0; eg < 4; ++eg) {
                const int e = eg * 16 + l15;
                const float c0 = bf2f(cp[e]);
                const float c1 = bf2f(cp[64 + e]);
                const float c2 = bf2f(cp[128 + e]);
                #pragma unroll
                for (int r = 0; r < 4; ++r) {
                    m1[eg][r][0] += c0 * d[eg][r];
                    m1[eg][r][1] += c1 * d[eg][r];
                    m1[eg][r][2] += c2 * d[eg][r];
                }
            }
        }
        A0 = nA0; A1 = nA1;
    }

    // ---------------- cross-wave reduce into msgS (aliases h0/h1/x0-head) --
    __syncthreads();
    for (int idx = t; idx < 64 * 81; idx += 256) msgS[idx] = 0.f;
    __syncthreads();
    if (w <= 2) {   // quarters 0,1,2 produced msg0
        #pragma unroll
        for (int eg = 0; eg < 4; ++eg) {
            float* mb = msgS + (eg * 16 + l15) * 81;
            #pragma unroll
            for (int hs = 0; hs < 2; ++hs)
                #pragma unroll
                for (int r = 0; r < 4; ++r)
                    atomicAdd(&mb[hs * 16 + lq * 4 + r], m0[eg][hs][r]);
        }
    }
    if (w >= 2) {   // quarters 2,3 produced msg1
        #pragma unroll
        for (int eg = 0; eg < 4; ++eg) {
            float* mb = msgS + (eg * 16 + l15) * 81 + 32;
            #pragma unroll
            for (int r = 0; r < 4; ++r)
                #pragma unroll
                for (int k = 0; k < 3; ++k)
                    atomicAdd(&mb[(lq * 4 + r) * 3 + k], m1[eg][r][k]);
        }
    }
    __syncthreads();

    // ---------------- global scatter ---------------------------------------
    for (int idx = t; idx < 64 * 81; idx += 256) {
        const int e = idx / 81;
        const int s = idx - e * 81;
        if (s < 80)
            atomicAdd(out + (size_t)dstS[e] * 80 + s, msgS[idx]);
    }
}

extern "C" void kernel_launch(void* const* d_in, const int* in_sizes, int n_in,
                              void* d_out, int out_size, void* d_ws, size_t ws_size,
                              hipStream_t stream) {
    const int*   eidx       = (const int*)d_in[0];
    const float* node_feat  = (const float*)d_in[1];
    const float* edge_feat  = (const float*)d_in[2];
    const float* edge_embed = (const float*)d_in[3];
    const float* Wfc0       = (const float*)d_in[5];
    const float* Wfc1       = (const float*)d_in[6];
    const float* Wfc2       = (const float*)d_in[7];
    const float* Wsc0       = (const float*)d_in[8];
    const float* Wsc1       = (const float*)d_in[9];
    float* out = (float*)d_out;
    u16*   ws  = (u16*)d_ws;

    if (ws_size < (size_t)WS_ELEMS * sizeof(u16)) return;  // need 344 KB scratch

    hipLaunchKernelGGL(k_pre, dim3(WS_ELEMS / 256), dim3(256), 0, stream,
                       Wfc0, Wfc1, Wfc2, ws);
    hipLaunchKernelGGL(k_selfconn, dim3((NNODES * 80 + 255) / 256), dim3(256), 0, stream,
                       node_feat, Wsc0, Wsc1, out);
    hipLaunchKernelGGL(k_main, dim3(NEDGES / 64), dim3(256), 0, stream,
                       eidx, node_feat, edge_feat, edge_embed, ws, out);
}

// Round 3
// 93.637 us; speedup vs baseline: 14.9742x; 1.4985x over previous
//
#include <hip/hip_runtime.h>

typedef unsigned short u16;
typedef __bf16 bf16x8 __attribute__((ext_vector_type(8)));
typedef float  f32x4  __attribute__((ext_vector_type(4)));

#define NEDGES 65536
#define NNODES 8192

#define PW0f       0.14433756729740643f   // (1/48)^0.5
#define PW1f       0.21650635094610965f   // (3/64)^0.5
#define INV_SQRT3f 0.5773502691896258f
#define INV_SQRT6f 0.4082482904638631f
#define SILU_NORMf 1.6790425f

// workspace layout (bf16 elements)
#define WT2_OFF 0          // [2560][64]  Wfc2^T, 0.125*region scale folded
#define WT0_OFF 163840     // [64][64]    Wfc0^T * 0.125
#define WT1_OFF 167936     // [64][64]    Wfc1^T * 0.125
#define WS_ELEMS 172032

#define HSTR 72            // padded bf16 row stride for h0/h1 LDS tiles

__device__ __forceinline__ float silu_n(float z) {
    return SILU_NORMf * z / (1.0f + __expf(-z));
}
__device__ __forceinline__ u16 f2bf(float f) {
    return __builtin_bit_cast(u16, (__bf16)f);
}
__device__ __forceinline__ float bf2f(u16 u) {
    unsigned v = ((unsigned)u) << 16;
    return __builtin_bit_cast(float, v);
}
__device__ __forceinline__ bf16x8 ld_bf8(const u16* p) {
    return *reinterpret_cast<const bf16x8*>(p);
}
__device__ __forceinline__ bf16x8 cvt_bf8(const float* p) {
    float4 a = *reinterpret_cast<const float4*>(p);
    float4 b = *reinterpret_cast<const float4*>(p + 4);
    bf16x8 r;
    r[0]=(__bf16)a.x; r[1]=(__bf16)a.y; r[2]=(__bf16)a.z; r[3]=(__bf16)a.w;
    r[4]=(__bf16)b.x; r[5]=(__bf16)b.y; r[6]=(__bf16)b.z; r[7]=(__bf16)b.w;
    return r;
}
#define MFMA16(A,B,C) __builtin_amdgcn_mfma_f32_16x16x32_bf16(A,B,C,0,0,0)

// ---------------------------------------------------------------------------
// Prep kernel (fused): blocks [0,672) transpose+scale+bf16 the MLP weights
// into d_ws; blocks [672,3232) compute the self-connection into d_out
// (re-initializes d_out every call).
// ---------------------------------------------------------------------------
__global__ void k_prep(const float* __restrict__ Wfc0,
                       const float* __restrict__ Wfc1,
                       const float* __restrict__ Wfc2,
                       const float* __restrict__ node_feat,
                       const float* __restrict__ Wsc0,
                       const float* __restrict__ Wsc1,
                       u16* __restrict__ ws,
                       float* __restrict__ out)
{
    const int bid = blockIdx.x;
    if (bid < 672) {
        int gid = bid * 256 + threadIdx.x;
        if (gid < 163840) {                 // gid = k*2560 + j (read-coalesced)
            int k = gid / 2560;
            int j = gid - k * 2560;
            float s;
            if (j < 1024)      s = PW0f;
            else if (j < 1536) s = PW0f * INV_SQRT3f;
            else if (j < 2304) s = PW1f * INV_SQRT3f;
            else               s = PW1f * INV_SQRT6f;
            ws[WT2_OFF + j * 64 + k] = f2bf(Wfc2[gid] * (0.125f * s));
        } else if (gid < WT1_OFF) {
            int i = gid - WT0_OFF;
            int k = i >> 6, n = i & 63;
            ws[WT0_OFF + n * 64 + k] = f2bf(Wfc0[i] * 0.125f);
        } else if (gid < WS_ELEMS) {
            int i = gid - WT1_OFF;
            int k = i >> 6, n = i & 63;
            ws[WT1_OFF + n * 64 + k] = f2bf(Wfc1[i] * 0.125f);
        }
    } else {
        int gid = (bid - 672) * 256 + threadIdx.x;
        if (gid >= NNODES * 80) return;
        int n = gid / 80;
        int s = gid - n * 80;
        const float* nf = node_feat + (size_t)n * 80;
        float r;
        if (s < 32) {
            float a = 0.f;
            #pragma unroll
            for (int u = 0; u < 32; ++u) a += nf[u] * Wsc0[u * 32 + s];
            r = a * 0.17677669529663687f;   // 1/sqrt(32)
        } else {
            int v = (s - 32) / 3;
            int k = (s - 32) - v * 3;
            float a = 0.f;
            #pragma unroll
            for (int u = 0; u < 16; ++u) a += nf[32 + u * 3 + k] * Wsc1[u * 16 + v];
            r = a * 0.25f;                   // 1/sqrt(16)
        }
        out[gid] = r;
    }
}

// ---------------------------------------------------------------------------
// Main fused kernel: 64 edges / block, 4 waves.
// Wave roles (rotated per block for cross-SIMD balance):
//   role 0: fc2 tiles [0,48)    -> msg0  (W1 u=0..23)
//   role 1: tiles [48,96)       -> msg0  (W1 u=24..31 + W2)
//   role 2: tiles [96,128)      -> msg1  (W3)
//   role 3: tiles [128,160)     -> msg1  (W4 + W5)
// Epilogue coefs pre-folded with y0/y1 into bf16 LDS tables:
//   c12S[u][e]  u<32: x0*y0 ; u in [32,48): dot(x1,y1)
//   coefB[row][e] rows (u'*3+k), u'<32: x0[u']*y1[k]; u' in [32,48): x1*y0;
//                 u' in [48,64): cross(x1,y1)
// Main loop: manually 2-stage software-pipelined (A pair prefetched 2 tiles
// ahead), runtime trip count (no unroll blowup).
// ---------------------------------------------------------------------------
__global__ __launch_bounds__(256, 3) void k_main(
    const int*   __restrict__ eidx,
    const float* __restrict__ node_feat,
    const float* __restrict__ edge_feat,
    const float* __restrict__ edge_embed,
    const u16*   __restrict__ ws,
    float*       __restrict__ out)
{
    __shared__ __align__(16) char smem[40192];
    u16*   h1S   = (u16*)(smem);            // [64][72]  9216 B
    u16*   c12S  = (u16*)(smem + 9216);     // [48][64]  6144 B
    u16*   coefB = (u16*)(smem + 15360);    // [192][64] 24576 B
    int*   dstS  = (int*)(smem + 39936);    // 256 B
    u16*   h0S   = (u16*)(smem + 15360);    // alias: [64][72] during fc phase
    float* msgS  = (float*)(smem + 9216);   // alias: [64][81] f32 = 20736 B at reduce

    const int t    = threadIdx.x;
    const int lane = t & 63;
    const int l15  = lane & 15;
    const int lq   = lane >> 4;
    const int wid  = t >> 6;
    const int role = (wid + blockIdx.x) & 3;
    const int eg0  = blockIdx.x * 64;

    const u16* WT2 = ws + WT2_OFF;
    const u16* WT0 = ws + WT0_OFF;
    const u16* WT1 = ws + WT1_OFF;

    // ---------------- fc0: h0 = silu(emb @ W0/8), 16 edges per wave --------
    {
        const float* erow = edge_embed + (size_t)(eg0 + wid * 16 + l15) * 64 + 8 * lq;
        bf16x8 eB0 = cvt_bf8(erow);
        bf16x8 eB1 = cvt_bf8(erow + 32);
        #pragma unroll
        for (int ntl = 0; ntl < 4; ++ntl) {
            const u16* a = WT0 + (ntl * 16 + l15) * 64 + 8 * lq;
            bf16x8 A0 = ld_bf8(a);
            bf16x8 A1 = ld_bf8(a + 32);
            f32x4 z = {0.f, 0.f, 0.f, 0.f};
            z = MFMA16(A0, eB0, z);
            f32x4 dd = MFMA16(A1, eB1, z);
            ushort4 pk;
            pk.x = f2bf(silu_n(dd[0]));
            pk.y = f2bf(silu_n(dd[1]));
            pk.z = f2bf(silu_n(dd[2]));
            pk.w = f2bf(silu_n(dd[3]));
            *(ushort4*)&h0S[(wid * 16 + l15) * HSTR + ntl * 16 + lq * 4] = pk;
        }
    }
    // ---------------- fc1: h1 = silu(h0 @ W1/8) (own rows; no barrier) -----
    {
        const u16* hrow = h0S + (wid * 16 + l15) * HSTR + 8 * lq;
        bf16x8 hB0 = ld_bf8(hrow);
        bf16x8 hB1 = ld_bf8(hrow + 32);
        #pragma unroll
        for (int ntl = 0; ntl < 4; ++ntl) {
            const u16* a = WT1 + (ntl * 16 + l15) * 64 + 8 * lq;
            bf16x8 A0 = ld_bf8(a);
            bf16x8 A1 = ld_bf8(a + 32);
            f32x4 z = {0.f, 0.f, 0.f, 0.f};
            z = MFMA16(A0, hB0, z);
            f32x4 dd = MFMA16(A1, hB1, z);
            ushort4 pk;
            pk.x = f2bf(silu_n(dd[0]));
            pk.y = f2bf(silu_n(dd[1]));
            pk.z = f2bf(silu_n(dd[2]));
            pk.w = f2bf(silu_n(dd[3]));
            *(ushort4*)&h1S[(wid * 16 + l15) * HSTR + ntl * 16 + lq * 4] = pk;
        }
    }
    __syncthreads();   // h0S (coefB alias) gets overwritten next; h1S published

    // ---------------- left-factor coef tables, 4 threads per edge ----------
    {
        const int e   = t & 63;
        const int q   = t >> 6;
        const int eg  = eg0 + e;
        const int src = eidx[eg];
        const float* nf = node_feat + (size_t)src * 80;
        const float* ef = edge_feat + (size_t)eg * 4;
        if (q == 0) {
            dstS[e] = eidx[NEDGES + eg];
            const float y0 = ef[0];
            #pragma unroll
            for (int u = 0; u < 32; ++u) c12S[u * 64 + e] = f2bf(nf[u] * y0);
        } else if (q == 1) {
            const float ya = ef[1], yb = ef[2], yc = ef[3];
            #pragma unroll
            for (int u = 0; u < 16; ++u) {
                float d = nf[32 + u * 3] * ya + nf[32 + u * 3 + 1] * yb
                        + nf[32 + u * 3 + 2] * yc;
                c12S[(32 + u) * 64 + e] = f2bf(d);
            }
        } else if (q == 2) {
            const float ya = ef[1], yb = ef[2], yc = ef[3];
            #pragma unroll
            for (int u = 0; u < 32; ++u) {
                const float x = nf[u];
                coefB[(u * 3 + 0) * 64 + e] = f2bf(x * ya);
                coefB[(u * 3 + 1) * 64 + e] = f2bf(x * yb);
                coefB[(u * 3 + 2) * 64 + e] = f2bf(x * yc);
            }
        } else {
            const float y0 = ef[0], ya = ef[1], yb = ef[2], yc = ef[3];
            #pragma unroll
            for (int u = 0; u < 16; ++u) {
                const float xa = nf[32 + u * 3], xb = nf[32 + u * 3 + 1], xc = nf[32 + u * 3 + 2];
                coefB[(96 + u * 3 + 0) * 64 + e] = f2bf(xa * y0);
                coefB[(96 + u * 3 + 1) * 64 + e] = f2bf(xb * y0);
                coefB[(96 + u * 3 + 2) * 64 + e] = f2bf(xc * y0);
                coefB[(144 + u * 3 + 0) * 64 + e] = f2bf(xb * yc - xc * yb);
                coefB[(144 + u * 3 + 1) * 64 + e] = f2bf(xc * ya - xa * yc);
                coefB[(144 + u * 3 + 2) * 64 + e] = f2bf(xa * yb - xb * ya);
            }
        }
    }
    __syncthreads();

    // ---------------- B fragments (all 64 edges) ---------------------------
    bf16x8 hb[4][2];
    #pragma unroll
    for (int eg = 0; eg < 4; ++eg) {
        const u16* r = h1S + (eg * 16 + l15) * HSTR + 8 * lq;
        hb[eg][0] = ld_bf8(r);
        hb[eg][1] = ld_bf8(r + 32);
    }

    float acc[48];
    #pragma unroll
    for (int i = 0; i < 48; ++i) acc[i] = 0.f;

    int t0, ntile;
    if (role < 2) { t0 = role * 48;            ntile = 48; }
    else          { t0 = 96 + (role - 2) * 32; ntile = 32; }

    const u16* Aw = WT2 + l15 * 64 + 8 * lq;   // + 1024 elems per tile

#define COMPUTE(A0_, A1_, D_)                                          \
    {                                                                  \
        _Pragma("unroll")                                              \
        for (int eg = 0; eg < 4; ++eg) {                               \
            f32x4 z = {0.f, 0.f, 0.f, 0.f};                            \
            z = MFMA16(A0_, hb[eg][0], z);                             \
            D_[eg] = MFMA16(A1_, hb[eg][1], z);                        \
        }                                                              \
    }

#define EPILOGUE(D_, TT_, HS_)                                              \
    {                                                                       \
        if (role < 2) {                                                     \
            const u16* cr = c12S + ((TT_) >> 1) * 64;                       \
            _Pragma("unroll")                                               \
            for (int eg = 0; eg < 4; ++eg) {                                \
                const float c = bf2f(cr[eg * 16 + l15]);                    \
                _Pragma("unroll")                                           \
                for (int r = 0; r < 4; ++r)                                 \
                    acc[eg * 8 + (HS_) * 4 + r] += c * D_[eg][r];           \
            }                                                               \
        } else {                                                            \
            const u16* cr = coefB + ((TT_) - 96) * 192;                     \
            _Pragma("unroll")                                               \
            for (int eg = 0; eg < 4; ++eg) {                                \
                const int e16 = eg * 16 + l15;                              \
                const float c0 = bf2f(cr[e16]);                             \
                const float c1 = bf2f(cr[64 + e16]);                        \
                const float c2 = bf2f(cr[128 + e16]);                       \
                _Pragma("unroll")                                           \
                for (int r = 0; r < 4; ++r) {                               \
                    const float dv = D_[eg][r];                             \
                    acc[eg * 12 + r * 3 + 0] += c0 * dv;                    \
                    acc[eg * 12 + r * 3 + 1] += c1 * dv;                    \
                    acc[eg * 12 + r * 3 + 2] += c2 * dv;                    \
                }                                                           \
            }                                                               \
        }                                                                   \
    }

    // ---------------- main fc2 loop: 2-stage pipeline ----------------------
    bf16x8 Aa0, Aa1, Ab0, Ab1;
    {
        const u16* p = Aw + (size_t)t0 * 1024;
        Aa0 = ld_bf8(p); Aa1 = ld_bf8(p + 32);
        const u16* q = Aw + (size_t)(t0 + 1) * 1024;
        Ab0 = ld_bf8(q); Ab1 = ld_bf8(q + 32);
    }
    const int np = ntile >> 1;
    #pragma unroll 1
    for (int p = 0; p < np; ++p) {
        const int tt = t0 + 2 * p;
        bf16x8 Ac0, Ac1, Ad0, Ad1;
        const bool more = (p + 1 < np);
        if (more) {
            const u16* q = Aw + (size_t)(tt + 2) * 1024;
            Ac0 = ld_bf8(q); Ac1 = ld_bf8(q + 32);
        }
        f32x4 d[4];
        COMPUTE(Aa0, Aa1, d);
        EPILOGUE(d, tt, 0);
        if (more) {
            const u16* q = Aw + (size_t)(tt + 3) * 1024;
            Ad0 = ld_bf8(q); Ad1 = ld_bf8(q + 32);
        }
        COMPUTE(Ab0, Ab1, d);
        EPILOGUE(d, tt + 1, 1);
        if (more) { Aa0 = Ac0; Aa1 = Ac1; Ab0 = Ad0; Ab1 = Ad1; }
    }
#undef COMPUTE
#undef EPILOGUE

    // ---------------- cross-wave reduce (owner-ordered, no atomics) --------
    __syncthreads();   // all waves done reading c12S/coefB; msgS aliases them
    if (role == 0) {
        #pragma unroll
        for (int eg = 0; eg < 4; ++eg) {
            float* mb = msgS + (eg * 16 + l15) * 81;
            #pragma unroll
            for (int hs = 0; hs < 2; ++hs)
                #pragma unroll
                for (int r = 0; r < 4; ++r)
                    mb[hs * 16 + lq * 4 + r] = acc[eg * 8 + hs * 4 + r];
        }
    } else if (role == 2) {
        #pragma unroll
        for (int eg = 0; eg < 4; ++eg) {
            float* mb = msgS + (eg * 16 + l15) * 81 + 32;
            #pragma unroll
            for (int r = 0; r < 4; ++r)
                #pragma unroll
                for (int k = 0; k < 3; ++k)
                    mb[(lq * 4 + r) * 3 + k] = acc[eg * 12 + r * 3 + k];
        }
    }
    __syncthreads();
    if (role == 1) {
        #pragma unroll
        for (int eg = 0; eg < 4; ++eg) {
            float* mb = msgS + (eg * 16 + l15) * 81;
            #pragma unroll
            for (int hs = 0; hs < 2; ++hs)
                #pragma unroll
                for (int r = 0; r < 4; ++r)
                    mb[hs * 16 + lq * 4 + r] += acc[eg * 8 + hs * 4 + r];
        }
    } else if (role == 3) {
        #pragma unroll
        for (int eg = 0; eg < 4; ++eg) {
            float* mb = msgS + (eg * 16 + l15) * 81 + 32;
            #pragma unroll
            for (int r = 0; r < 4; ++r)
                #pragma unroll
                for (int k = 0; k < 3; ++k)
                    mb[(lq * 4 + r) * 3 + k] += acc[eg * 12 + r * 3 + k];
        }
    }
    __syncthreads();

    // ---------------- global scatter ---------------------------------------
    for (int idx = t; idx < 64 * 81; idx += 256) {
        const int e = idx / 81;
        const int s = idx - e * 81;
        if (s < 80)
            atomicAdd(out + (size_t)dstS[e] * 80 + s, msgS[idx]);
    }
}

extern "C" void kernel_launch(void* const* d_in, const int* in_sizes, int n_in,
                              void* d_out, int out_size, void* d_ws, size_t ws_size,
                              hipStream_t stream) {
    const int*   eidx       = (const int*)d_in[0];
    const float* node_feat  = (const float*)d_in[1];
    const float* edge_feat  = (const float*)d_in[2];
    const float* edge_embed = (const float*)d_in[3];
    const float* Wfc0       = (const float*)d_in[5];
    const float* Wfc1       = (const float*)d_in[6];
    const float* Wfc2       = (const float*)d_in[7];
    const float* Wsc0       = (const float*)d_in[8];
    const float* Wsc1       = (const float*)d_in[9];
    float* out = (float*)d_out;
    u16*   ws  = (u16*)d_ws;

    if (ws_size < (size_t)WS_ELEMS * sizeof(u16)) return;  // need 344 KB scratch

    hipLaunchKernelGGL(k_prep, dim3(672 + 2560), dim3(256), 0, stream,
                       Wfc0, Wfc1, Wfc2, node_feat, Wsc0, Wsc1, ws, out);
    hipLaunchKernelGGL(k_main, dim3(NEDGES / 64), dim3(256), 0, stream,
                       eidx, node_feat, edge_feat, edge_embed, ws, out);
}